// Round 1
// baseline (290.832 us; speedup 1.0000x reference)
//
#include <hip/hip_runtime.h>

// Gaussian pyramid, 4 levels.
// Input: im (16,3,1024,1024) f32. Output: concat of levels 0..3 flat, f32.
// Level0 = copy. Level k+1 = edge-pad-2 + 5x5 separable conv (stride 2).

__global__ void gpyr_copy(const float4* __restrict__ in, float4* __restrict__ out, int n4) {
    int i = blockIdx.x * blockDim.x + threadIdx.x;
    int stride = gridDim.x * blockDim.x;
    for (; i < n4; i += stride) out[i] = in[i];
}

__global__ void gpyr_reduce(const float* __restrict__ in, float* __restrict__ out,
                            int Hin, int Win, int Hout, int Wout) {
    const int ox = blockIdx.x * blockDim.x + threadIdx.x;
    const int oy = blockIdx.y * blockDim.y + threadIdx.y;
    const int img = blockIdx.z;  // n*c flat (48 images)
    if (ox >= Wout || oy >= Hout) return;

    const float* ip = in + (size_t)img * Hin * Win;
    const float k0 = 0.0625f, k1 = 0.25f, k2 = 0.375f;
    const float kk[5] = {k0, k1, k2, k1, k0};

    float acc = 0.0f;
#pragma unroll
    for (int ky = 0; ky < 5; ++ky) {
        int iy = 2 * oy + ky - 2;
        iy = min(max(iy, 0), Hin - 1);
        const float* rp = ip + (size_t)iy * Win;
        float h = 0.0f;
#pragma unroll
        for (int kx = 0; kx < 5; ++kx) {
            int ix = 2 * ox + kx - 2;
            ix = min(max(ix, 0), Win - 1);
            h += kk[kx] * rp[ix];
        }
        acc += kk[ky] * h;
    }
    out[(size_t)img * Hout * Wout + (size_t)oy * Wout + ox] = acc;
}

extern "C" void kernel_launch(void* const* d_in, const int* in_sizes, int n_in,
                              void* d_out, int out_size, void* d_ws, size_t ws_size,
                              hipStream_t stream) {
    const float* im = (const float*)d_in[0];
    float* out = (float*)d_out;

    const int NC = 16 * 3;              // 48 images
    const size_t L0 = (size_t)NC * 1024 * 1024;  // 50331648
    const size_t L1 = (size_t)NC * 512 * 512;    // 12582912
    const size_t L2 = (size_t)NC * 256 * 256;    // 3145728

    float* out0 = out;
    float* out1 = out0 + L0;
    float* out2 = out1 + L1;
    float* out3 = out2 + L2;

    // Level 0: straight copy, float4 vectorized grid-stride.
    {
        int n4 = (int)(L0 / 4);
        int block = 256;
        int grid = 2048;  // 256 CU * 8, grid-stride
        gpyr_copy<<<grid, block, 0, stream>>>((const float4*)im, (float4*)out0, n4);
    }

    // Levels 1..3: stride-2 separable 5x5 with replicate-pad-2.
    auto launch_reduce = [&](const float* src, float* dst, int Hin, int Win) {
        int Hout = Hin / 2, Wout = Win / 2;
        dim3 block(64, 4, 1);
        dim3 grid((Wout + 63) / 64, (Hout + 3) / 4, NC);
        gpyr_reduce<<<grid, block, 0, stream>>>(src, dst, Hin, Win, Hout, Wout);
    };

    launch_reduce(im,   out1, 1024, 1024);
    launch_reduce(out1, out2, 512, 512);
    launch_reduce(out2, out3, 256, 256);
}

// Round 2
// 199.047 us; speedup vs baseline: 1.4611x; 1.4611x over previous
//
#include <hip/hip_runtime.h>

// Gaussian pyramid, 4 levels. Input (16,3,1024,1024) f32.
// Level0 = copy. Level k+1 = replicate-pad-2 + separable 5x5, stride 2.

__global__ void gpyr_copy(const float4* __restrict__ in, float4* __restrict__ out, int n4) {
    int i = blockIdx.x * blockDim.x + threadIdx.x;
    int stride = gridDim.x * blockDim.x;
    for (; i < n4; i += stride) out[i] = in[i];
}

// Each thread computes 4 consecutive output pixels (one float4 store).
// Loads 16 input floats per row (4x float4, aligned), vertical pass into
// 11 register accumulators, then horizontal pass.
__global__ void gpyr_reduce2(const float* __restrict__ in, float* __restrict__ out,
                             int Hin, int Win, int Hout, int Wout) {
    const int ox0 = (blockIdx.x * blockDim.x + threadIdx.x) * 4;  // first output x
    const int oy  = blockIdx.y * blockDim.y + threadIdx.y;
    const int img = blockIdx.z;
    if (ox0 >= Wout || oy >= Hout) return;

    const float k0 = 0.0625f, k1 = 0.25f, k2 = 0.375f;
    const float kk[5] = {k0, k1, k2, k1, k0};

    const float* ip = in + (size_t)img * Hin * Win;

    // Need input x in [2*ox0-2, 2*ox0+8]  (11 values, v[0..10]).
    // Aligned 16-float window: xbase = 2*ox0 - 4  (multiple of 4).
    const int xbase = 2 * ox0 - 4;
    const bool edge = (xbase < 0) || (xbase + 16 > Win);

    float v[11];
#pragma unroll
    for (int i = 0; i < 11; ++i) v[i] = 0.0f;

#pragma unroll
    for (int ky = 0; ky < 5; ++ky) {
        int iy = 2 * oy + ky - 2;
        iy = min(max(iy, 0), Hin - 1);
        const float* rp = ip + (size_t)iy * Win;
        const float w = kk[ky];
        if (!edge) {
            const float4* rp4 = (const float4*)(rp + xbase);
            float4 a = rp4[0], b = rp4[1], c = rp4[2], d = rp4[3];
            // v[i] corresponds to input x = xbase + 2 + i
            v[0] += w * a.z;  v[1] += w * a.w;
            v[2] += w * b.x;  v[3] += w * b.y;  v[4] += w * b.z;  v[5] += w * b.w;
            v[6] += w * c.x;  v[7] += w * c.y;  v[8] += w * c.z;  v[9] += w * c.w;
            v[10] += w * d.x;
        } else {
#pragma unroll
            for (int i = 0; i < 11; ++i) {
                int ix = 2 * ox0 - 2 + i;
                ix = min(max(ix, 0), Win - 1);
                v[i] += w * rp[ix];
            }
        }
    }

    float4 o;
    o.x = k0 * v[0] + k1 * v[1] + k2 * v[2] + k1 * v[3] + k0 * v[4];
    o.y = k0 * v[2] + k1 * v[3] + k2 * v[4] + k1 * v[5] + k0 * v[6];
    o.z = k0 * v[4] + k1 * v[5] + k2 * v[6] + k1 * v[7] + k0 * v[8];
    o.w = k0 * v[6] + k1 * v[7] + k2 * v[8] + k1 * v[9] + k0 * v[10];

    *(float4*)(out + (size_t)img * Hout * Wout + (size_t)oy * Wout + ox0) = o;
}

extern "C" void kernel_launch(void* const* d_in, const int* in_sizes, int n_in,
                              void* d_out, int out_size, void* d_ws, size_t ws_size,
                              hipStream_t stream) {
    const float* im = (const float*)d_in[0];
    float* out = (float*)d_out;

    const int NC = 16 * 3;
    const size_t L0 = (size_t)NC * 1024 * 1024;
    const size_t L1 = (size_t)NC * 512 * 512;
    const size_t L2 = (size_t)NC * 256 * 256;

    float* out0 = out;
    float* out1 = out0 + L0;
    float* out2 = out1 + L1;
    float* out3 = out2 + L2;

    // Level 0: straight copy.
    {
        int n4 = (int)(L0 / 4);
        gpyr_copy<<<2048, 256, 0, stream>>>((const float4*)im, (float4*)out0, n4);
    }

    auto launch_reduce = [&](const float* src, float* dst, int Hin, int Win) {
        int Hout = Hin / 2, Wout = Win / 2;
        int tpx = Wout / 4;               // threads needed in x
        if (tpx > 64) tpx = 64;
        int tpy = 256 / tpx;
        dim3 block(tpx, tpy, 1);
        dim3 grid((Wout / 4 + tpx - 1) / tpx, (Hout + tpy - 1) / tpy, NC);
        gpyr_reduce2<<<grid, block, 0, stream>>>(src, dst, Hin, Win, Hout, Wout);
    };

    launch_reduce(im,   out1, 1024, 1024);
    launch_reduce(out1, out2, 512, 512);
    launch_reduce(out2, out3, 256, 256);
}

// Round 3
// 158.086 us; speedup vs baseline: 1.8397x; 1.2591x over previous
//
#include <hip/hip_runtime.h>

// Gaussian pyramid, 4 levels. Input (16,3,1024,1024) f32.
// Level0 = copy (fused into level-1 reduce). Level k+1 = replicate-pad-2 +
// separable 5x5, stride 2.

// Fused: each thread computes 4 consecutive out1 pixels AND copies its
// 2x8 owned input pixels to out0 (they are already in registers).
__global__ void gpyr_copy_reduce(const float* __restrict__ in,
                                 float* __restrict__ out0,
                                 float* __restrict__ out1,
                                 int Hin, int Win, int Hout, int Wout) {
    const int ox0 = (blockIdx.x * blockDim.x + threadIdx.x) * 4;
    const int oy  = blockIdx.y * blockDim.y + threadIdx.y;
    const int img = blockIdx.z;
    if (ox0 >= Wout || oy >= Hout) return;

    const float k0 = 0.0625f, k1 = 0.25f, k2 = 0.375f;
    const float kk[5] = {k0, k1, k2, k1, k0};

    const float* ip = in + (size_t)img * Hin * Win;

    const int xbase = 2 * ox0 - 4;
    const bool edge = (xbase < 0) || (xbase + 16 > Win);

    float v[11];
#pragma unroll
    for (int i = 0; i < 11; ++i) v[i] = 0.0f;

    float4 cp0a, cp0b, cp1a, cp1b;  // copy data: rows 2*oy, 2*oy+1, x [2*ox0, 2*ox0+8)

#pragma unroll
    for (int ky = 0; ky < 5; ++ky) {
        int iy = 2 * oy + ky - 2;
        iy = min(max(iy, 0), Hin - 1);
        const float* rp = ip + (size_t)iy * Win;
        const float w = kk[ky];
        if (!edge) {
            const float4* rp4 = (const float4*)(rp + xbase);
            float4 a = rp4[0], b = rp4[1], c = rp4[2], d = rp4[3];
            if (ky == 2) { cp0a = b; cp0b = c; }
            if (ky == 3) { cp1a = b; cp1b = c; }
            v[0] += w * a.z;  v[1] += w * a.w;
            v[2] += w * b.x;  v[3] += w * b.y;  v[4] += w * b.z;  v[5] += w * b.w;
            v[6] += w * c.x;  v[7] += w * c.y;  v[8] += w * c.z;  v[9] += w * c.w;
            v[10] += w * d.x;
        } else {
            // clamped conv loads
#pragma unroll
            for (int i = 0; i < 11; ++i) {
                int ix = 2 * ox0 - 2 + i;
                ix = min(max(ix, 0), Win - 1);
                v[i] += w * rp[ix];
            }
            // copy loads (always in range: 2*ox0+8 <= Win)
            if (ky == 2) {
                cp0a = *(const float4*)(rp + 2 * ox0);
                cp0b = *(const float4*)(rp + 2 * ox0 + 4);
            }
            if (ky == 3) {
                cp1a = *(const float4*)(rp + 2 * ox0);
                cp1b = *(const float4*)(rp + 2 * ox0 + 4);
            }
        }
    }

    // copy stores
    {
        float* op = out0 + (size_t)img * Hin * Win + (size_t)(2 * oy) * Win + 2 * ox0;
        *(float4*)(op)           = cp0a;
        *(float4*)(op + 4)       = cp0b;
        *(float4*)(op + Win)     = cp1a;
        *(float4*)(op + Win + 4) = cp1b;
    }

    float4 o;
    o.x = k0 * v[0] + k1 * v[1] + k2 * v[2] + k1 * v[3] + k0 * v[4];
    o.y = k0 * v[2] + k1 * v[3] + k2 * v[4] + k1 * v[5] + k0 * v[6];
    o.z = k0 * v[4] + k1 * v[5] + k2 * v[6] + k1 * v[7] + k0 * v[8];
    o.w = k0 * v[6] + k1 * v[7] + k2 * v[8] + k1 * v[9] + k0 * v[10];

    *(float4*)(out1 + (size_t)img * Hout * Wout + (size_t)oy * Wout + ox0) = o;
}

// Standalone reduce for levels 2,3 (same math, no copy).
__global__ void gpyr_reduce2(const float* __restrict__ in, float* __restrict__ out,
                             int Hin, int Win, int Hout, int Wout) {
    const int ox0 = (blockIdx.x * blockDim.x + threadIdx.x) * 4;
    const int oy  = blockIdx.y * blockDim.y + threadIdx.y;
    const int img = blockIdx.z;
    if (ox0 >= Wout || oy >= Hout) return;

    const float k0 = 0.0625f, k1 = 0.25f, k2 = 0.375f;
    const float kk[5] = {k0, k1, k2, k1, k0};

    const float* ip = in + (size_t)img * Hin * Win;
    const int xbase = 2 * ox0 - 4;
    const bool edge = (xbase < 0) || (xbase + 16 > Win);

    float v[11];
#pragma unroll
    for (int i = 0; i < 11; ++i) v[i] = 0.0f;

#pragma unroll
    for (int ky = 0; ky < 5; ++ky) {
        int iy = 2 * oy + ky - 2;
        iy = min(max(iy, 0), Hin - 1);
        const float* rp = ip + (size_t)iy * Win;
        const float w = kk[ky];
        if (!edge) {
            const float4* rp4 = (const float4*)(rp + xbase);
            float4 a = rp4[0], b = rp4[1], c = rp4[2], d = rp4[3];
            v[0] += w * a.z;  v[1] += w * a.w;
            v[2] += w * b.x;  v[3] += w * b.y;  v[4] += w * b.z;  v[5] += w * b.w;
            v[6] += w * c.x;  v[7] += w * c.y;  v[8] += w * c.z;  v[9] += w * c.w;
            v[10] += w * d.x;
        } else {
#pragma unroll
            for (int i = 0; i < 11; ++i) {
                int ix = 2 * ox0 - 2 + i;
                ix = min(max(ix, 0), Win - 1);
                v[i] += w * rp[ix];
            }
        }
    }

    float4 o;
    o.x = k0 * v[0] + k1 * v[1] + k2 * v[2] + k1 * v[3] + k0 * v[4];
    o.y = k0 * v[2] + k1 * v[3] + k2 * v[4] + k1 * v[5] + k0 * v[6];
    o.z = k0 * v[4] + k1 * v[5] + k2 * v[6] + k1 * v[7] + k0 * v[8];
    o.w = k0 * v[6] + k1 * v[7] + k2 * v[8] + k1 * v[9] + k0 * v[10];

    *(float4*)(out + (size_t)img * Hout * Wout + (size_t)oy * Wout + ox0) = o;
}

extern "C" void kernel_launch(void* const* d_in, const int* in_sizes, int n_in,
                              void* d_out, int out_size, void* d_ws, size_t ws_size,
                              hipStream_t stream) {
    const float* im = (const float*)d_in[0];
    float* out = (float*)d_out;

    const int NC = 16 * 3;
    const size_t L0 = (size_t)NC * 1024 * 1024;
    const size_t L1 = (size_t)NC * 512 * 512;
    const size_t L2 = (size_t)NC * 256 * 256;

    float* out0 = out;
    float* out1 = out0 + L0;
    float* out2 = out1 + L1;
    float* out3 = out2 + L2;

    // Fused level0 copy + level1 reduce.
    {
        int Hout = 512, Wout = 512;
        dim3 block(64, 4, 1);
        dim3 grid((Wout / 4) / 64, Hout / 4, NC);
        gpyr_copy_reduce<<<grid, block, 0, stream>>>(im, out0, out1, 1024, 1024, Hout, Wout);
    }

    auto launch_reduce = [&](const float* src, float* dst, int Hin, int Win) {
        int Hout = Hin / 2, Wout = Win / 2;
        int tpx = Wout / 4;
        if (tpx > 64) tpx = 64;
        int tpy = 256 / tpx;
        dim3 block(tpx, tpy, 1);
        dim3 grid((Wout / 4 + tpx - 1) / tpx, (Hout + tpy - 1) / tpy, NC);
        gpyr_reduce2<<<grid, block, 0, stream>>>(src, dst, Hin, Win, Hout, Wout);
    };

    launch_reduce(out1, out2, 512, 512);
    launch_reduce(out2, out3, 256, 256);
}